// Round 1
// 348.784 us; speedup vs baseline: 1.0490x; 1.0490x over previous
//
#include <hip/hip_runtime.h>
#include <hip/hip_bf16.h>
#include <stdint.h>

// QKV projection: C[M,N] = A[M,K] * W[N,K]^T + bias[N]
// M=16384, N=3072, K=1024, fp32 in/out, graded at bf16 tolerance.
// Stage 1 (unchanged): fused fp32->bf16 convert of A and W into d_ws.
// Stage 2 (NEW): 256x256 8-phase bf16 GEMM (m201-structure):
//   BK=64, 8 waves (2Mx4N), 128 KiB LDS double-buffer,
//   T1 XCD-bijective block swizzle, T2 full 3-bit LDS XOR swizzle
//   (inverse-swizzled global source + linear global_load_lds dest),
//   T3/T4 counted vmcnt(4) once per K-tile (never drained in main loop),
//   T5 s_setprio(1) around each 16-MFMA cluster.
// Stage schedule (derived, provably race-free under the 2-barrier phases):
//   ph1: read A[m0-3]+B[n0-1]  | stage A(t+1) half0 -> other buffer
//   ph2: read B[n2-3]          | stage A(t+1) half1 -> other buffer
//   ph3: read A[m4-7]          | stage B(t+2) half0 -> THIS buffer (B dead after ph2)
//   ph4: (no reads)            | stage B(t+2) half1; s_waitcnt vmcnt(4)
// At each tile boundary exactly B(t+2)'s 4 loads remain in flight.

typedef __attribute__((ext_vector_type(8))) short short8;            // 8 x bf16
typedef __attribute__((ext_vector_type(8))) unsigned short ushort8;  // 8 x bf16 bits
typedef __attribute__((ext_vector_type(4))) float f32x4;

#define MTOT 16384
#define NTOT 3072
#define KTOT 1024
#define NKT  16        // KTOT / 64
#define BUFS 65536     // one buffer: A region 32K + B region 32K
#define BREG 32768     // B region offset inside a buffer

// ws layout (bytes): A bf16 [M*K], then W bf16 [N*K]
#define WS_A_OFF   0u
#define WS_A_BYTES (MTOT * KTOT * 2u)   // 33554432
#define WS_W_OFF   (WS_A_OFF + WS_A_BYTES)

// ---- fused fp32->bf16 convert for A and W (unchanged, ~20us) ------------
__global__ __launch_bounds__(256) void cvt_aw(
    const float* __restrict__ A, const float* __restrict__ W,
    unsigned short* __restrict__ dA, unsigned short* __restrict__ dW)
{
    const float* src;
    unsigned short* dst;
    long i;
    if (blockIdx.x < 8192) {
        src = A; dst = dA;
        i = ((long)blockIdx.x * 256 + threadIdx.x) * 8;
    } else {
        src = W; dst = dW;
        i = ((long)(blockIdx.x - 8192) * 256 + threadIdx.x) * 8;
    }
    f32x4 a = *(const f32x4*)(src + i);
    f32x4 b = *(const f32x4*)(src + i + 4);
    ushort8 r;
    r[0] = __bfloat16_as_ushort(__float2bfloat16(a[0]));
    r[1] = __bfloat16_as_ushort(__float2bfloat16(a[1]));
    r[2] = __bfloat16_as_ushort(__float2bfloat16(a[2]));
    r[3] = __bfloat16_as_ushort(__float2bfloat16(a[3]));
    r[4] = __bfloat16_as_ushort(__float2bfloat16(b[0]));
    r[5] = __bfloat16_as_ushort(__float2bfloat16(b[1]));
    r[6] = __bfloat16_as_ushort(__float2bfloat16(b[2]));
    r[7] = __bfloat16_as_ushort(__float2bfloat16(b[3]));
    *(ushort8*)(dst + i) = r;
}

__device__ __forceinline__ void gload_lds16(const void* g, void* l) {
    __builtin_amdgcn_global_load_lds(
        (const __attribute__((address_space(1))) void*)g,
        (__attribute__((address_space(3))) void*)l,
        16, 0, 0);
}

// one C-quadrant: 4(M) x 2(N) fragments x 2 k-slices = 16 MFMAs
template<int IO, int JO>
__device__ __forceinline__ void mfma_quad(f32x4 (&acc)[8][4],
                                          const short8 (&a)[4][2],
                                          const short8 (&b)[4][2])
{
    #pragma unroll
    for (int i = 0; i < 4; ++i) {
        #pragma unroll
        for (int j = 0; j < 2; ++j) {
            f32x4 c = acc[IO + i][JO + j];
            c = __builtin_amdgcn_mfma_f32_16x16x32_bf16(a[i][0], b[JO + j][0], c, 0, 0, 0);
            c = __builtin_amdgcn_mfma_f32_16x16x32_bf16(a[i][1], b[JO + j][1], c, 0, 0, 0);
            acc[IO + i][JO + j] = c;
        }
    }
}

// one K-tile (BK=64), 4 phases. VM: vmcnt immediate at ph4 (-1 = none).
// SA: stage A(t+1) (ph1/ph2, into other buffer). SB: stage B(t+2) (ph3/ph4,
// into this buffer's B region). kA/kB = element column offsets of those tiles.
template<int VM, bool SA, bool SB>
__device__ __forceinline__ void ktile(
    char* sm, int curOff,
    const unsigned short* gA, const unsigned short* gB,
    int kA, int kB, int ra, int rb, int ch0, int w,
    f32x4 (&acc)[8][4])
{
    const int nxtOff = curOff ^ BUFS;
    char* stA = sm + nxtOff + w * 1024;          // wave-uniform stage bases
    char* stB = sm + curOff + BREG + w * 1024;
    const char* rdA = sm + curOff + ra;
    const char* rdB = sm + curOff + BREG + rb;
    const int c1 = ch0 ^ 64;                      // k-slice 1 chunk (swizzled)

    short8 aF[4][2], aG[4][2], bF[4][2];

    // ---------------- phase 1: A[m0-3] + B[n0-1] reads | stage A(t+1).h0
    #pragma unroll
    for (int i = 0; i < 4; ++i) {
        aF[i][0] = *(const short8*)(rdA + i * 2048 + ch0);
        aF[i][1] = *(const short8*)(rdA + i * 2048 + c1);
    }
    #pragma unroll
    for (int j = 0; j < 2; ++j) {
        bF[j][0] = *(const short8*)(rdB + j * 2048 + ch0);
        bF[j][1] = *(const short8*)(rdB + j * 2048 + c1);
    }
    if (SA) {
        gload_lds16(gA + kA,          stA);
        gload_lds16(gA + kA + 65536,  stA + 8192);
    }
    __builtin_amdgcn_s_barrier();
    __builtin_amdgcn_s_setprio(1);
    mfma_quad<0, 0>(acc, aF, bF);
    __builtin_amdgcn_s_setprio(0);
    __builtin_amdgcn_s_barrier();

    // ---------------- phase 2: B[n2-3] reads | stage A(t+1).h1
    #pragma unroll
    for (int j = 2; j < 4; ++j) {
        bF[j][0] = *(const short8*)(rdB + j * 2048 + ch0);
        bF[j][1] = *(const short8*)(rdB + j * 2048 + c1);
    }
    if (SA) {
        gload_lds16(gA + kA + 131072, stA + 16384);
        gload_lds16(gA + kA + 196608, stA + 24576);
    }
    __builtin_amdgcn_s_barrier();
    __builtin_amdgcn_s_setprio(1);
    mfma_quad<0, 2>(acc, aF, bF);
    __builtin_amdgcn_s_setprio(0);
    __builtin_amdgcn_s_barrier();

    // ---------------- phase 3: A[m4-7] reads | stage B(t+2).h0 (B region dead)
    #pragma unroll
    for (int i = 0; i < 4; ++i) {
        aG[i][0] = *(const short8*)(rdA + (i + 4) * 2048 + ch0);
        aG[i][1] = *(const short8*)(rdA + (i + 4) * 2048 + c1);
    }
    if (SB) {
        gload_lds16(gB + kB,          stB);
        gload_lds16(gB + kB + 65536,  stB + 8192);
    }
    __builtin_amdgcn_s_barrier();
    __builtin_amdgcn_s_setprio(1);
    mfma_quad<4, 0>(acc, aG, bF);
    __builtin_amdgcn_s_setprio(0);
    __builtin_amdgcn_s_barrier();

    // ---------------- phase 4: stage B(t+2).h1 | counted vmcnt | MFMA
    if (SB) {
        gload_lds16(gB + kB + 131072, stB + 16384);
        gload_lds16(gB + kB + 196608, stB + 24576);
    }
    if constexpr (VM == 4)      asm volatile("s_waitcnt vmcnt(4)" ::: "memory");
    else if constexpr (VM == 0) asm volatile("s_waitcnt vmcnt(0)" ::: "memory");
    __builtin_amdgcn_s_barrier();
    __builtin_amdgcn_s_setprio(1);
    mfma_quad<4, 2>(acc, aG, bF);
    __builtin_amdgcn_s_setprio(0);
    __builtin_amdgcn_s_barrier();
}

__global__ __launch_bounds__(512, 2) void qkv_gemm_8ph(
    const unsigned short* __restrict__ A,   // [M,K] bf16 bits (ws)
    const unsigned short* __restrict__ W,   // [N,K] bf16 bits (ws)
    const float* __restrict__ bias,         // [N] f32
    float* __restrict__ C)                  // [M,N] f32
{
    __shared__ __align__(16) char sm[2 * BUFS];   // 128 KiB

    const int t    = threadIdx.x;
    const int l    = t & 63;
    const int w    = t >> 6;
    const int fr   = l & 15;
    const int quad = l >> 4;

    // T1: XCD-bijective swizzle; 768 blocks = 8 XCDs x 96.
    // Consecutive idx share an A-panel (same mt) -> each XCD streams 8 panels.
    const int bid = blockIdx.x;
    const int idx = (bid & 7) * 96 + (bid >> 3);
    const int mt = idx / 12, nt = idx % 12;
    const int m0 = mt * 256, n0 = nt * 256;

    const int wm = w >> 2, wn = w & 3;     // 2 M-warps x 4 N-warps
    const int wrow = wm * 128, wcol = wn * 64;

    // staging source: thread covers 16B chunk; chunk index inverse-XOR-swizzled
    // so the linear global_load_lds dest yields swizzled LDS (rule #21).
    const int srow = w * 8 + (l >> 3);
    const int schk = ((l & 7) ^ (l >> 3)) << 3;    // element offset in row
    const unsigned short* gA = A + (size_t)(m0 + srow) * KTOT + schk;
    const unsigned short* gB = W + (size_t)(n0 + srow) * KTOT + schk;

    // LDS read: phys chunk = logical chunk ^ (row&7); row&7 == fr&7 here.
    const int ra  = (wrow + fr) * 128;
    const int rb  = (wcol + fr) * 128;
    const int ch0 = (quad ^ (fr & 7)) << 4;        // k-slice 0 chunk byte off

    f32x4 acc[8][4];
    #pragma unroll
    for (int i = 0; i < 8; ++i)
        #pragma unroll
        for (int j = 0; j < 4; ++j)
            acc[i][j] = (f32x4){0.f, 0.f, 0.f, 0.f};

    // prologue: stage tile0 B+A (buf0) and tile1 B (buf1); land tile0 only.
    {
        char* stA  = sm + w * 1024;
        char* stB  = sm + BREG + w * 1024;
        char* stB1 = sm + BUFS + BREG + w * 1024;
        gload_lds16(gB,                stB);
        gload_lds16(gB + 65536,        stB + 8192);
        gload_lds16(gB + 131072,       stB + 16384);
        gload_lds16(gB + 196608,       stB + 24576);
        gload_lds16(gA,                stA);
        gload_lds16(gA + 65536,        stA + 8192);
        gload_lds16(gA + 131072,       stA + 16384);
        gload_lds16(gA + 196608,       stA + 24576);
        gload_lds16(gB + 64,           stB1);
        gload_lds16(gB + 64 + 65536,   stB1 + 8192);
        gload_lds16(gB + 64 + 131072,  stB1 + 16384);
        gload_lds16(gB + 64 + 196608,  stB1 + 24576);
        asm volatile("s_waitcnt vmcnt(4)" ::: "memory");  // tile0 landed, tile1.B in flight
        __builtin_amdgcn_s_barrier();
    }

    int curOff = 0;
    for (int kt = 0; kt < NKT - 2; ++kt) {             // t = 0..13
        ktile<4, true, true>(sm, curOff, gA, gB,
                             (kt + 1) * 64, (kt + 2) * 64, ra, rb, ch0, w, acc);
        curOff ^= BUFS;
    }
    // t = 14: stage A(15) only, drain fully at ph4.
    ktile<0, true, false>(sm, curOff, gA, gB, 15 * 64, 0, ra, rb, ch0, w, acc);
    curOff ^= BUFS;
    // t = 15: no staging, no waits.
    ktile<-1, false, false>(sm, curOff, gA, gB, 0, 0, ra, rb, ch0, w, acc);

    // epilogue: C/D layout col=lane&15, row=quad*4+reg (m89-verified)
    float bv[4];
    #pragma unroll
    for (int j = 0; j < 4; ++j)
        bv[j] = bias[n0 + wcol + j * 16 + fr];

    #pragma unroll
    for (int i = 0; i < 8; ++i) {
        const int row = m0 + wrow + i * 16 + quad * 4;
        #pragma unroll
        for (int j = 0; j < 4; ++j) {
            float* p = C + (size_t)row * NTOT + (n0 + wcol + j * 16 + fr);
            #pragma unroll
            for (int r = 0; r < 4; ++r)
                p[(size_t)r * NTOT] = acc[i][j][r] + bv[j];
        }
    }
}

extern "C" void kernel_launch(void* const* d_in, const int* in_sizes, int n_in,
                              void* d_out, int out_size, void* d_ws, size_t ws_size,
                              hipStream_t stream) {
    const float* q  = (const float*)d_in[0];
    const float* Wq = (const float*)d_in[1];
    const float* bq = (const float*)d_in[2];
    float*       C  = (float*)d_out;

    char* ws = (char*)d_ws;
    unsigned short* wsA = (unsigned short*)(ws + WS_A_OFF);
    unsigned short* wsW = (unsigned short*)(ws + WS_W_OFF);

    cvt_aw<<<8192 + 1536, 256, 0, stream>>>(q, Wq, wsA, wsW);

    qkv_gemm_8ph<<<dim3(768), dim3(512), 0, stream>>>(wsA, wsW, bq, C);
}

// Round 2
// 338.305 us; speedup vs baseline: 1.0815x; 1.0310x over previous
//
#include <hip/hip_runtime.h>
#include <hip/hip_bf16.h>
#include <stdint.h>

// QKV projection: C[M,N] = A[M,K] * W[N,K]^T + bias[N]
// M=16384, N=3072, K=1024, fp32 in/out, graded at bf16 tolerance.
// Stage 1: fused fp32->bf16 convert of A and W into d_ws (unchanged).
// Stage 2 (v3): 256x256 bf16 GEMM, 8-phase / 2-K-tile iteration with a
//   ONE-PHASE-AHEAD ds_read pipeline (reads issue under the previous
//   quadrant's MFMA), 2 barriers + 1 vmcnt(0) per K-tile (both with
//   multi-phase slack), stage-(t+2)-into-current-buffer, T1 XCD swizzle,
//   T2 full 3-bit LDS XOR swizzle, T5 setprio around MFMA clusters.
// Safety: explicit lgkmcnt(0) before every barrier => barrier arrival
//   implies all of this wave's LDS reads completed (rule-18-proof; does
//   not rely on compiler MFMA placement). vmcnt(0) at ph2-end guarantees
//   the next tile's staged data landed before any cross-buffer ds_read.

typedef __attribute__((ext_vector_type(8))) short short8;            // 8 x bf16
typedef __attribute__((ext_vector_type(8))) unsigned short ushort8;  // 8 x bf16 bits
typedef __attribute__((ext_vector_type(4))) float f32x4;

#define MTOT 16384
#define NTOT 3072
#define KTOT 1024
#define NKT  16        // KTOT / 64
#define BUFS 65536     // one buffer: A region 32K + B region 32K
#define BREG 32768     // B region offset inside a buffer

#define WS_A_OFF   0u
#define WS_A_BYTES (MTOT * KTOT * 2u)
#define WS_W_OFF   (WS_A_OFF + WS_A_BYTES)

#define WAIT_LGKM0 asm volatile("s_waitcnt lgkmcnt(0)" ::: "memory")
#define WAIT_VM0   asm volatile("s_waitcnt vmcnt(0)" ::: "memory")
#define BARRIER    __builtin_amdgcn_s_barrier()

// ---- fused fp32->bf16 convert for A and W (unchanged) -------------------
__global__ __launch_bounds__(256) void cvt_aw(
    const float* __restrict__ A, const float* __restrict__ W,
    unsigned short* __restrict__ dA, unsigned short* __restrict__ dW)
{
    const float* src;
    unsigned short* dst;
    long i;
    if (blockIdx.x < 8192) {
        src = A; dst = dA;
        i = ((long)blockIdx.x * 256 + threadIdx.x) * 8;
    } else {
        src = W; dst = dW;
        i = ((long)(blockIdx.x - 8192) * 256 + threadIdx.x) * 8;
    }
    f32x4 a = *(const f32x4*)(src + i);
    f32x4 b = *(const f32x4*)(src + i + 4);
    ushort8 r;
    r[0] = __bfloat16_as_ushort(__float2bfloat16(a[0]));
    r[1] = __bfloat16_as_ushort(__float2bfloat16(a[1]));
    r[2] = __bfloat16_as_ushort(__float2bfloat16(a[2]));
    r[3] = __bfloat16_as_ushort(__float2bfloat16(a[3]));
    r[4] = __bfloat16_as_ushort(__float2bfloat16(b[0]));
    r[5] = __bfloat16_as_ushort(__float2bfloat16(b[1]));
    r[6] = __bfloat16_as_ushort(__float2bfloat16(b[2]));
    r[7] = __bfloat16_as_ushort(__float2bfloat16(b[3]));
    *(ushort8*)(dst + i) = r;
}

__device__ __forceinline__ void gload_lds16(const void* g, void* l) {
    __builtin_amdgcn_global_load_lds(
        (const __attribute__((address_space(1))) void*)g,
        (__attribute__((address_space(3))) void*)l,
        16, 0, 0);
}

// stage one 256x64 operand tile quarter-by-quarter (4 x global_load_lds,
// each call: 8 waves x 64 lanes x 16B = rows srow..srow+63)
__device__ __forceinline__ void stage4(const unsigned short* g, char* l) {
    gload_lds16(g,          l);
    gload_lds16(g + 65536,  l + 8192);
    gload_lds16(g + 131072, l + 16384);
    gload_lds16(g + 196608, l + 24576);
}

// fragment loads (swizzled chunk addressing; ch0^64 = k-slice 1)
__device__ __forceinline__ void rd_a4(short8 (&d)[4][2], const char* base, int ch0) {
    const int c1 = ch0 ^ 64;
    #pragma unroll
    for (int i = 0; i < 4; ++i) {
        d[i][0] = *(const short8*)(base + i * 2048 + ch0);
        d[i][1] = *(const short8*)(base + i * 2048 + c1);
    }
}
__device__ __forceinline__ void rd_b2(short8 (&d)[2][2], const char* base, int ch0) {
    const int c1 = ch0 ^ 64;
    #pragma unroll
    for (int j = 0; j < 2; ++j) {
        d[j][0] = *(const short8*)(base + j * 2048 + ch0);
        d[j][1] = *(const short8*)(base + j * 2048 + c1);
    }
}

// one C-quadrant: 4(M) x 2(N) fragments x 2 k-slices = 16 MFMAs
template<int IO, int JO>
__device__ __forceinline__ void quad(f32x4 (&acc)[8][4],
                                     const short8 (&a)[4][2],
                                     const short8 (&b)[2][2])
{
    __builtin_amdgcn_s_setprio(1);
    #pragma unroll
    for (int i = 0; i < 4; ++i) {
        #pragma unroll
        for (int j = 0; j < 2; ++j) {
            f32x4 c = acc[IO + i][JO + j];
            c = __builtin_amdgcn_mfma_f32_16x16x32_bf16(a[i][0], b[j][0], c, 0, 0, 0);
            c = __builtin_amdgcn_mfma_f32_16x16x32_bf16(a[i][1], b[j][1], c, 0, 0, 0);
            acc[IO + i][JO + j] = c;
        }
    }
    __builtin_amdgcn_s_setprio(0);
}

// One pair of K-tiles (t even -> buf0, t+1 -> buf1), 8 phases, reads one
// phase ahead. STG: stage tiles t+2/t+3. PF: prefetch next pair's aA/bA.
template<bool STG, bool PF>
__device__ __forceinline__ void kpair(
    char* sm, const unsigned short* gA, const unsigned short* gB,
    int kE2, int kO2, int ra, int rb, int ch0, int w,
    short8 (&aAe)[4][2], short8 (&aBe)[4][2], short8 (&bAe)[2][2], short8 (&bBe)[2][2],
    short8 (&aAo)[4][2], short8 (&aBo)[4][2], short8 (&bAo)[2][2], short8 (&bBo)[2][2],
    f32x4 (&acc)[8][4])
{
    const char* rA0 = sm + ra;          const char* rB0 = sm + BREG + rb;
    const char* rA1 = sm + BUFS + ra;   const char* rB1 = sm + BUFS + BREG + rb;
    char* sA0 = sm + w * 1024;          char* sB0 = sm + BREG + w * 1024;
    char* sA1 = sA0 + BUFS;             char* sB1 = sB0 + BUFS;

    // ph1(e): read bBe (for ph2) | Q00(aAe,bAe)
    rd_b2(bBe, rB0 + 4096, ch0);
    quad<0, 0>(acc, aAe, bAe);

    // ph2(e): read aBe (for ph3) | Q02(aAe,bBe) | drain: t+1 data landed
    rd_a4(aBe, rA0 + 8192, ch0);
    quad<0, 2>(acc, aAe, bBe);
    WAIT_LGKM0; WAIT_VM0; BARRIER;

    // ph3(e): read aAo (t+1, buf1) | stage B(t+2)->buf0-B | Q40(aBe,bAe)
    rd_a4(aAo, rA1, ch0);
    if (STG) stage4(gB + kE2, sB0);
    quad<4, 0>(acc, aBe, bAe);
    WAIT_LGKM0; BARRIER;

    // ph4(e): read bAo (t+1) | stage A(t+2)->buf0-A | Q42(aBe,bBe)
    rd_b2(bAo, rB1, ch0);
    if (STG) stage4(gA + kE2, sA0);
    quad<4, 2>(acc, aBe, bBe);

    // ph1(o): read bBo | Q00(aAo,bAo)          (barrier-free span)
    rd_b2(bBo, rB1 + 4096, ch0);
    quad<0, 0>(acc, aAo, bAo);

    // ph2(o): read aBo | Q02(aAo,bBo) | drain: t+2 data landed
    rd_a4(aBo, rA1 + 8192, ch0);
    quad<0, 2>(acc, aAo, bBo);
    WAIT_LGKM0; WAIT_VM0; BARRIER;

    // ph3(o): read aAe (t+2, buf0) | stage B(t+3)->buf1-B | Q40(aBo,bAo)
    if (PF) rd_a4(aAe, rA0, ch0);
    if (STG) stage4(gB + kO2, sB1);
    quad<4, 0>(acc, aBo, bAo);
    WAIT_LGKM0; BARRIER;

    // ph4(o): read bAe (t+2) | stage A(t+3)->buf1-A | Q42(aBo,bBo)
    if (PF) rd_b2(bAe, rB0, ch0);
    if (STG) stage4(gA + kO2, sA1);
    quad<4, 2>(acc, aBo, bBo);
}

__global__ __launch_bounds__(512, 2) void qkv_gemm_8ph(
    const unsigned short* __restrict__ A,   // [M,K] bf16 bits (ws)
    const unsigned short* __restrict__ W,   // [N,K] bf16 bits (ws)
    const float* __restrict__ bias,         // [N] f32
    float* __restrict__ C)                  // [M,N] f32
{
    __shared__ __align__(16) char sm[2 * BUFS];   // 128 KiB

    const int t    = threadIdx.x;
    const int l    = t & 63;
    const int w    = t >> 6;
    const int fr   = l & 15;
    const int quad_= l >> 4;

    // T1: XCD-bijective swizzle; 768 blocks = 8 XCDs x 96 (96 = 8 A-panels).
    const int bid = blockIdx.x;
    const int idx = (bid & 7) * 96 + (bid >> 3);
    const int mt = idx / 12, nt = idx % 12;
    const int m0 = mt * 256, n0 = nt * 256;

    const int wm = w >> 2, wn = w & 3;     // 2 M-warps x 4 N-warps
    const int wrow = wm * 128, wcol = wn * 64;

    // staging source: inverse-XOR-swizzled column so the linear
    // global_load_lds dest yields swizzled LDS (rule #21).
    const int srow = w * 8 + (l >> 3);
    const int schk = ((l & 7) ^ (l >> 3)) << 3;
    const unsigned short* gA = A + (size_t)(m0 + srow) * KTOT + schk;
    const unsigned short* gB = W + (size_t)(n0 + srow) * KTOT + schk;

    // LDS read: phys chunk = logical chunk ^ (row&7); row&7 == fr&7 here.
    const int ra  = (wrow + fr) * 128;
    const int rb  = (wcol + fr) * 128;
    const int ch0 = (quad_ ^ (fr & 7)) << 4;

    f32x4 acc[8][4];
    #pragma unroll
    for (int i = 0; i < 8; ++i)
        #pragma unroll
        for (int j = 0; j < 4; ++j)
            acc[i][j] = (f32x4){0.f, 0.f, 0.f, 0.f};

    short8 aAe[4][2], aBe[4][2], bAe[2][2], bBe[2][2];
    short8 aAo[4][2], aBo[4][2], bAo[2][2], bBo[2][2];

    // prologue: stage tile0 -> buf0, tile1 -> buf1; land tile0; prefetch
    // tile0's aA,bA fragments.
    {
        char* sA0 = sm + w * 1024;   char* sB0 = sm + BREG + w * 1024;
        char* sA1 = sA0 + BUFS;      char* sB1 = sB0 + BUFS;
        stage4(gA,      sA0);
        stage4(gB,      sB0);
        stage4(gA + 64, sA1);
        stage4(gB + 64, sB1);
        asm volatile("s_waitcnt vmcnt(8)" ::: "memory");  // tile0 landed
        BARRIER;
        rd_a4(aAe, sm + ra, ch0);
        rd_b2(bAe, sm + BREG + rb, ch0);
    }

    #pragma unroll 1
    for (int p = 0; p < 7; ++p) {                 // tiles 0..13, stage 2..15
        kpair<true, true>(sm, gA, gB, (2 * p + 2) * 64, (2 * p + 3) * 64,
                          ra, rb, ch0, w,
                          aAe, aBe, bAe, bBe, aAo, aBo, bAo, bBo, acc);
    }
    // tail pair: tiles 14,15 — no staging, no next-pair prefetch.
    kpair<false, false>(sm, gA, gB, 0, 0, ra, rb, ch0, w,
                        aAe, aBe, bAe, bBe, aAo, aBo, bAo, bBo, acc);

    // epilogue: C/D layout col=lane&15, row=quad*4+reg (m89-verified)
    float bv[4];
    #pragma unroll
    for (int j = 0; j < 4; ++j)
        bv[j] = bias[n0 + wcol + j * 16 + fr];

    #pragma unroll
    for (int i = 0; i < 8; ++i) {
        const int row = m0 + wrow + i * 16 + quad_ * 4;
        #pragma unroll
        for (int j = 0; j < 4; ++j) {
            float* p = C + (size_t)row * NTOT + (n0 + wcol + j * 16 + fr);
            #pragma unroll
            for (int r = 0; r < 4; ++r)
                p[(size_t)r * NTOT] = acc[i][j][r] + bv[j];
        }
    }
}

extern "C" void kernel_launch(void* const* d_in, const int* in_sizes, int n_in,
                              void* d_out, int out_size, void* d_ws, size_t ws_size,
                              hipStream_t stream) {
    const float* q  = (const float*)d_in[0];
    const float* Wq = (const float*)d_in[1];
    const float* bq = (const float*)d_in[2];
    float*       C  = (float*)d_out;

    char* ws = (char*)d_ws;
    unsigned short* wsA = (unsigned short*)(ws + WS_A_OFF);
    unsigned short* wsW = (unsigned short*)(ws + WS_W_OFF);

    cvt_aw<<<8192 + 1536, 256, 0, stream>>>(q, Wq, wsA, wsW);

    qkv_gemm_8ph<<<dim3(768), dim3(512), 0, stream>>>(wsA, wsW, bq, C);
}